// Round 1
// baseline (491.139 us; speedup 1.0000x reference)
//
#include <hip/hip_runtime.h>
#include <math.h>

constexpr int D = 64;          // D_IN == D_OUT == 64

__device__ inline void fma4(float4& a, float s, const float4& w) {
    a.x = fmaf(s, w.x, a.x);
    a.y = fmaf(s, w.y, a.y);
    a.z = fmaf(s, w.z, a.z);
    a.w = fmaf(s, w.w, a.w);
}

// deg[i] = 1.0 (self loop)
__global__ void k_init_deg(float* __restrict__ deg, int N) {
    int i = blockIdx.x * blockDim.x + threadIdx.x;
    if (i < N) deg[i] = 1.0f;
}

// deg[col[e]] += 1
__global__ void k_count_deg(const int* __restrict__ col, float* __restrict__ deg, int E) {
    int i = blockIdx.x * blockDim.x + threadIdx.x;
    if (i < E) atomicAdd(&deg[col[i]], 1.0f);
}

// h = x @ W ; g = dinv * h ; acc = g  (self-loop contribution pre-seeded)
__global__ __launch_bounds__(256) void k_gemm_scale(
        const float* __restrict__ x, const float* __restrict__ W,
        const float* __restrict__ deg,
        float* __restrict__ g, float* __restrict__ acc, int N) {
    __shared__ float4 Wl[D * D / 4];     // 16 KiB: Wl[k*16 + j4]
    const int tid = threadIdx.x;
    const float4* W4 = reinterpret_cast<const float4*>(W);
    for (int i = tid; i < D * D / 4; i += 256) Wl[i] = W4[i];
    __syncthreads();

    const int node = blockIdx.x * 256 + tid;
    if (node >= N) return;

    const float4* xr = reinterpret_cast<const float4*>(x + (size_t)node * D);

    float4 a[16];
#pragma unroll
    for (int j = 0; j < 16; ++j) a[j] = make_float4(0.f, 0.f, 0.f, 0.f);

    for (int k4 = 0; k4 < 16; ++k4) {       // dynamic loop, static inner indices
        const float4 xv = xr[k4];
#pragma unroll
        for (int j4 = 0; j4 < 16; ++j4) {
            // LDS reads are wave-uniform addresses -> broadcast, conflict-free
            float4 w0 = Wl[(4 * k4 + 0) * 16 + j4];
            float4 w1 = Wl[(4 * k4 + 1) * 16 + j4];
            float4 w2 = Wl[(4 * k4 + 2) * 16 + j4];
            float4 w3 = Wl[(4 * k4 + 3) * 16 + j4];
            fma4(a[j4], xv.x, w0);
            fma4(a[j4], xv.y, w1);
            fma4(a[j4], xv.z, w2);
            fma4(a[j4], xv.w, w3);
        }
    }

    const float dinv = rsqrtf(deg[node]);
    float4* g4   = reinterpret_cast<float4*>(g   + (size_t)node * D);
    float4* acc4 = reinterpret_cast<float4*>(acc + (size_t)node * D);
#pragma unroll
    for (int j4 = 0; j4 < 16; ++j4) {
        float4 v = a[j4];
        v.x *= dinv; v.y *= dinv; v.z *= dinv; v.w *= dinv;
        g4[j4]   = v;
        acc4[j4] = v;
    }
}

// one edge per wave: lane j does acc[c][j] += g[r][j]
__global__ __launch_bounds__(256) void k_scatter(
        const int* __restrict__ ei, const float* __restrict__ g,
        float* __restrict__ acc, int E) {
    const int gid  = blockIdx.x * 256 + threadIdx.x;
    const int e    = gid >> 6;
    const int lane = threadIdx.x & 63;
    if (e >= E) return;
    const int r = ei[e];        // source
    const int c = ei[E + e];    // target
    const float v = g[(size_t)r * D + lane];
    atomicAdd(acc + (size_t)c * D + lane, v);
}

// out = dinv[c] * acc + b
__global__ void k_finalize(const float* __restrict__ deg, const float* __restrict__ b,
                           float* __restrict__ out, int N) {
    const int idx = blockIdx.x * blockDim.x + threadIdx.x;
    if (idx >= N * D) return;
    const int node = idx >> 6;
    const int j    = idx & 63;
    out[idx] = rsqrtf(deg[node]) * out[idx] + b[j];
}

extern "C" void kernel_launch(void* const* d_in, const int* in_sizes, int n_in,
                              void* d_out, int out_size, void* d_ws, size_t ws_size,
                              hipStream_t stream) {
    const float* x  = (const float*)d_in[0];
    const int*   ei = (const int*)d_in[1];
    const float* W  = (const float*)d_in[2];
    const float* b  = (const float*)d_in[3];
    float* out = (float*)d_out;

    const int N = in_sizes[0] / D;     // 100000
    const int E = in_sizes[1] / 2;     // 1600000

    float* g   = (float*)d_ws;                    // N*D floats = 25.6 MB
    float* deg = g + (size_t)N * D;               // N floats   = 0.4 MB

    k_init_deg <<<(N + 255) / 256, 256, 0, stream>>>(deg, N);
    k_count_deg<<<(E + 255) / 256, 256, 0, stream>>>(ei + E, deg, E);
    k_gemm_scale<<<(N + 255) / 256, 256, 0, stream>>>(x, W, deg, g, out, N);

    // one wave (64 threads) per edge -> E*64 threads, 4 edges per 256-block
    k_scatter<<<(E + 3) / 4, 256, 0, stream>>>(ei, g, out, E);

    k_finalize<<<(N * D + 255) / 256, 256, 0, stream>>>(deg, b, out, N);
}

// Round 2
// 312.566 us; speedup vs baseline: 1.5713x; 1.5713x over previous
//
#include <hip/hip_runtime.h>
#include <math.h>

constexpr int D = 64;          // D_IN == D_OUT == 64
constexpr int SCAN_CHUNK = 2048;  // 256 threads x 8

__device__ inline void fma4(float4& a, float s, const float4& w) {
    a.x = fmaf(s, w.x, a.x);
    a.y = fmaf(s, w.y, a.y);
    a.z = fmaf(s, w.z, a.z);
    a.w = fmaf(s, w.w, a.w);
}

__global__ void k_zero_i32(int* __restrict__ p, int n) {
    int i = blockIdx.x * blockDim.x + threadIdx.x;
    if (i < n) p[i] = 0;
}

// cnt[col[e]] += 1  (int atomics into 400 KB array — cheap)
__global__ void k_hist(const int* __restrict__ col, int* __restrict__ cnt, int E) {
    int i = blockIdx.x * blockDim.x + threadIdx.x;
    if (i < E) atomicAdd(&cnt[col[i]], 1);
}

// per-chunk exclusive scan; offs[i] = exclusive prefix within chunk; sums[b] = chunk total
__global__ __launch_bounds__(256) void k_scan_a(const int* __restrict__ cnt,
                                                int* __restrict__ offs,
                                                int* __restrict__ sums, int N) {
    __shared__ int lds[256];
    const int t = threadIdx.x;
    const int base = blockIdx.x * SCAN_CHUNK;
    int v[8];
    int s = 0;
#pragma unroll
    for (int k = 0; k < 8; ++k) {
        int idx = base + t * 8 + k;
        v[k] = (idx < N) ? cnt[idx] : 0;
        s += v[k];
    }
    lds[t] = s;
    __syncthreads();
    for (int off = 1; off < 256; off <<= 1) {
        int y = (t >= off) ? lds[t - off] : 0;
        __syncthreads();
        if (t >= off) lds[t] += y;
        __syncthreads();
    }
    int run = lds[t] - s;   // exclusive prefix of this thread's 8 elements
#pragma unroll
    for (int k = 0; k < 8; ++k) {
        int idx = base + t * 8 + k;
        if (idx < N) offs[idx] = run;
        run += v[k];
    }
    if (t == 255) sums[blockIdx.x] = lds[255];
}

// exclusive scan of the (tiny) chunk-sum array, in place
__global__ void k_scan_b(int* __restrict__ sums, int n) {
    if (blockIdx.x == 0 && threadIdx.x == 0) {
        int run = 0;
        for (int i = 0; i < n; ++i) { int v = sums[i]; sums[i] = run; run += v; }
    }
}

// offs[i] += sums[i/CHUNK]; cursor[i] = offs[i]
__global__ void k_scan_c(int* __restrict__ offs, int* __restrict__ cursor,
                         const int* __restrict__ sums, int N) {
    int i = blockIdx.x * blockDim.x + threadIdx.x;
    if (i < N) {
        int o = offs[i] + sums[i / SCAN_CHUNK];
        offs[i] = o;
        cursor[i] = o;
    }
}

// scatter source index into its target's CSR segment
__global__ void k_fill(const int* __restrict__ ei, int* __restrict__ cursor,
                       int* __restrict__ srcIdx, int E) {
    int e = blockIdx.x * blockDim.x + threadIdx.x;
    if (e < E) {
        int r = ei[e];
        int c = ei[E + e];
        int p = atomicAdd(&cursor[c], 1);
        srcIdx[p] = r;
    }
}

// h = x @ W ; g = dinv * h   (optionally also seed acc=g for fallback path)
__global__ __launch_bounds__(256) void k_gemm_scale(
        const float* __restrict__ x, const float* __restrict__ W,
        const int* __restrict__ cnt,
        float* __restrict__ g, float* __restrict__ acc, int N) {
    __shared__ float4 Wl[D * D / 4];     // 16 KiB: Wl[k*16 + j4]
    const int tid = threadIdx.x;
    const float4* W4 = reinterpret_cast<const float4*>(W);
    for (int i = tid; i < D * D / 4; i += 256) Wl[i] = W4[i];
    __syncthreads();

    const int node = blockIdx.x * 256 + tid;
    if (node >= N) return;

    const float4* xr = reinterpret_cast<const float4*>(x + (size_t)node * D);

    float4 a[16];
#pragma unroll
    for (int j = 0; j < 16; ++j) a[j] = make_float4(0.f, 0.f, 0.f, 0.f);

    for (int k4 = 0; k4 < 16; ++k4) {
        const float4 xv = xr[k4];
#pragma unroll
        for (int j4 = 0; j4 < 16; ++j4) {
            float4 w0 = Wl[(4 * k4 + 0) * 16 + j4];
            float4 w1 = Wl[(4 * k4 + 1) * 16 + j4];
            float4 w2 = Wl[(4 * k4 + 2) * 16 + j4];
            float4 w3 = Wl[(4 * k4 + 3) * 16 + j4];
            fma4(a[j4], xv.x, w0);
            fma4(a[j4], xv.y, w1);
            fma4(a[j4], xv.z, w2);
            fma4(a[j4], xv.w, w3);
        }
    }

    const float dinv = rsqrtf((float)(cnt[node] + 1));
    float4* g4 = reinterpret_cast<float4*>(g + (size_t)node * D);
#pragma unroll
    for (int j4 = 0; j4 < 16; ++j4) {
        float4 v = a[j4];
        v.x *= dinv; v.y *= dinv; v.z *= dinv; v.w *= dinv;
        g4[j4] = v;
    }
    if (acc) {
        float4* acc4 = reinterpret_cast<float4*>(acc + (size_t)node * D);
#pragma unroll
        for (int j4 = 0; j4 < 16; ++j4) acc4[j4] = g4[j4];
    }
}

// one wave per node: 4 lane-groups of 16 handle 4 edges/iter, float4 per lane.
// acc = g[node] (self loop) + sum_{r in segment} g[r]; out = dinv*acc + b
__global__ __launch_bounds__(256) void k_reduce(
        const int* __restrict__ offs, const int* __restrict__ cnt,
        const int* __restrict__ srcIdx, const float* __restrict__ g,
        const float* __restrict__ b, float* __restrict__ out, int N) {
    const int node = blockIdx.x * 4 + (threadIdx.x >> 6);
    if (node >= N) return;
    const int lane = threadIdx.x & 63;
    const int grp  = lane >> 4;   // which edge slot (0..3)
    const int fl   = lane & 15;   // which float4 of the row

    const float4* g4 = reinterpret_cast<const float4*>(g);
    const int beg = offs[node];
    const int num = cnt[node];

    float4 acc = (grp == 0) ? g4[(size_t)node * 16 + fl]
                            : make_float4(0.f, 0.f, 0.f, 0.f);

    for (int i = beg + grp; i < beg + num; i += 4) {
        const int r = srcIdx[i];
        const float4 v = g4[(size_t)r * 16 + fl];
        acc.x += v.x; acc.y += v.y; acc.z += v.z; acc.w += v.w;
    }

    // combine the 4 lane-groups (xor 16, then 32)
#pragma unroll
    for (int off = 16; off <= 32; off <<= 1) {
        acc.x += __shfl_xor(acc.x, off, 64);
        acc.y += __shfl_xor(acc.y, off, 64);
        acc.z += __shfl_xor(acc.z, off, 64);
        acc.w += __shfl_xor(acc.w, off, 64);
    }

    if (grp == 0) {
        const float dinv = rsqrtf((float)(num + 1));
        const float4 bb = reinterpret_cast<const float4*>(b)[fl];
        float4 o;
        o.x = fmaf(dinv, acc.x, bb.x);
        o.y = fmaf(dinv, acc.y, bb.y);
        o.z = fmaf(dinv, acc.z, bb.z);
        o.w = fmaf(dinv, acc.w, bb.w);
        reinterpret_cast<float4*>(out)[(size_t)node * 16 + fl] = o;
    }
}

// ---- fallback path (atomic scatter), used only if ws is too small ----
__global__ void k_init_degf(float* __restrict__ deg, int N) {
    int i = blockIdx.x * blockDim.x + threadIdx.x;
    if (i < N) deg[i] = 1.0f;
}
__global__ void k_count_degf(const int* __restrict__ col, float* __restrict__ deg, int E) {
    int i = blockIdx.x * blockDim.x + threadIdx.x;
    if (i < E) atomicAdd(&deg[col[i]], 1.0f);
}
__global__ __launch_bounds__(256) void k_gemm_scale_f(
        const float* __restrict__ x, const float* __restrict__ W,
        const float* __restrict__ deg,
        float* __restrict__ g, float* __restrict__ acc, int N) {
    __shared__ float4 Wl[D * D / 4];
    const int tid = threadIdx.x;
    const float4* W4 = reinterpret_cast<const float4*>(W);
    for (int i = tid; i < D * D / 4; i += 256) Wl[i] = W4[i];
    __syncthreads();
    const int node = blockIdx.x * 256 + tid;
    if (node >= N) return;
    const float4* xr = reinterpret_cast<const float4*>(x + (size_t)node * D);
    float4 a[16];
#pragma unroll
    for (int j = 0; j < 16; ++j) a[j] = make_float4(0.f, 0.f, 0.f, 0.f);
    for (int k4 = 0; k4 < 16; ++k4) {
        const float4 xv = xr[k4];
#pragma unroll
        for (int j4 = 0; j4 < 16; ++j4) {
            fma4(a[j4], xv.x, Wl[(4 * k4 + 0) * 16 + j4]);
            fma4(a[j4], xv.y, Wl[(4 * k4 + 1) * 16 + j4]);
            fma4(a[j4], xv.z, Wl[(4 * k4 + 2) * 16 + j4]);
            fma4(a[j4], xv.w, Wl[(4 * k4 + 3) * 16 + j4]);
        }
    }
    const float dinv = rsqrtf(deg[node]);
    float4* g4   = reinterpret_cast<float4*>(g + (size_t)node * D);
    float4* acc4 = reinterpret_cast<float4*>(acc + (size_t)node * D);
#pragma unroll
    for (int j4 = 0; j4 < 16; ++j4) {
        float4 v = a[j4];
        v.x *= dinv; v.y *= dinv; v.z *= dinv; v.w *= dinv;
        g4[j4] = v; acc4[j4] = v;
    }
}
__global__ __launch_bounds__(256) void k_scatter_f(
        const int* __restrict__ ei, const float* __restrict__ g,
        float* __restrict__ acc, int E) {
    const int gid = blockIdx.x * 256 + threadIdx.x;
    const int e = gid >> 6;
    const int lane = threadIdx.x & 63;
    if (e >= E) return;
    atomicAdd(acc + (size_t)ei[E + e] * D + lane, g[(size_t)ei[e] * D + lane]);
}
__global__ void k_finalize_f(const float* __restrict__ deg, const float* __restrict__ b,
                             float* __restrict__ out, int N) {
    const int idx = blockIdx.x * blockDim.x + threadIdx.x;
    if (idx >= N * D) return;
    out[idx] = rsqrtf(deg[idx >> 6]) * out[idx] + b[idx & 63];
}

extern "C" void kernel_launch(void* const* d_in, const int* in_sizes, int n_in,
                              void* d_out, int out_size, void* d_ws, size_t ws_size,
                              hipStream_t stream) {
    const float* x  = (const float*)d_in[0];
    const int*   ei = (const int*)d_in[1];
    const float* W  = (const float*)d_in[2];
    const float* b  = (const float*)d_in[3];
    float* out = (float*)d_out;

    const int N = in_sizes[0] / D;     // 100000
    const int E = in_sizes[1] / 2;     // 1600000
    const int nChunks = (N + SCAN_CHUNK - 1) / SCAN_CHUNK;

    // ws layout (CSR path)
    size_t need = (size_t)N * D * 4      // g
                + (size_t)N * 4 * 3      // cnt, offs, cursor
                + (size_t)E * 4          // srcIdx
                + (size_t)(nChunks + 64) * 4;

    if (ws_size >= need) {
        float* g      = (float*)d_ws;
        int*   cnt    = (int*)(g + (size_t)N * D);
        int*   offs   = cnt + N;
        int*   cursor = offs + N;
        int*   srcIdx = cursor + N;
        int*   sums   = srcIdx + E;

        k_zero_i32<<<(N + 255) / 256, 256, 0, stream>>>(cnt, N);
        k_hist    <<<(E + 255) / 256, 256, 0, stream>>>(ei + E, cnt, E);
        k_scan_a  <<<nChunks, 256, 0, stream>>>(cnt, offs, sums, N);
        k_scan_b  <<<1, 64, 0, stream>>>(sums, nChunks);
        k_scan_c  <<<(N + 255) / 256, 256, 0, stream>>>(offs, cursor, sums, N);
        k_fill    <<<(E + 255) / 256, 256, 0, stream>>>(ei, cursor, srcIdx, E);
        k_gemm_scale<<<(N + 255) / 256, 256, 0, stream>>>(x, W, cnt, g, nullptr, N);
        k_reduce  <<<(N + 3) / 4, 256, 0, stream>>>(offs, cnt, srcIdx, g, b, out, N);
    } else {
        // fallback: atomic scatter (round-1 behavior)
        float* g   = (float*)d_ws;
        float* deg = g + (size_t)N * D;
        k_init_degf <<<(N + 255) / 256, 256, 0, stream>>>(deg, N);
        k_count_degf<<<(E + 255) / 256, 256, 0, stream>>>(ei + E, deg, E);
        k_gemm_scale_f<<<(N + 255) / 256, 256, 0, stream>>>(x, W, deg, g, out, N);
        k_scatter_f <<<(E + 3) / 4, 256, 0, stream>>>(ei, g, out, E);
        k_finalize_f<<<(N * D + 255) / 256, 256, 0, stream>>>(deg, b, out, N);
    }
}